// Round 1
// 1022.049 us; speedup vs baseline: 1.1131x; 1.1131x over previous
//
#include <hip/hip_runtime.h>
#include <hip/hip_bf16.h>
#include <stdint.h>

// Problem constants (B=2, N=512, DIM=INNER=EDGE_DIM=256, H=8, DH=32)
#define NB 2
#define NN 512
#define NDIM 256
#define NH 8
#define NDH 32
#define SCALE 0.17677669529663687f  // 32^-0.5

// ---------------------------------------------------------------------------
// K1: per-row projections (all f32).  (unchanged — models to ~30 µs)
// ---------------------------------------------------------------------------
__global__ __launch_bounds__(256) void k_proj(
    const float* __restrict__ nodes, const float* __restrict__ Wq, const float* __restrict__ bq,
    const float* __restrict__ Wkv, const float* __restrict__ bkv,
    const float* __restrict__ We, const float* __restrict__ be,
    float* __restrict__ q, float* __restrict__ k, float* __restrict__ v,
    float* __restrict__ qe, float* __restrict__ qbe)
{
    const int row = blockIdx.x;      // b*N + n
    const int t = threadIdx.x;
    __shared__ float xs[NDIM];
    __shared__ float qs[NDIM];
    xs[t] = nodes[(size_t)row*NDIM + t];
    __syncthreads();

    float accq = bq[t];
    float acck = bkv[t];
    float accv = bkv[t + NDIM];
    #pragma unroll 4
    for (int d = 0; d < NDIM; ++d) {
        float x = xs[d];
        accq += x * Wq[(size_t)d*NDIM + t];
        acck += x * Wkv[(size_t)d*2*NDIM + t];
        accv += x * Wkv[(size_t)d*2*NDIM + t + NDIM];
    }
    q[(size_t)row*NDIM + t] = accq;
    k[(size_t)row*NDIM + t] = acck;
    v[(size_t)row*NDIM + t] = accv;
    qs[t] = accq;
    __syncthreads();

    // qe: thread t owns We row c=t (contiguous 1KB -> float4 loads)
    float qacc[NH];
    #pragma unroll
    for (int h = 0; h < NH; ++h) qacc[h] = 0.f;
    const float* wrow = We + (size_t)t*NDIM;
    #pragma unroll
    for (int h = 0; h < NH; ++h) {
        float a0 = 0.f, a1 = 0.f, a2 = 0.f, a3 = 0.f;
        #pragma unroll
        for (int d4 = 0; d4 < NDH/4; ++d4) {
            float4 w4 = *(const float4*)(wrow + h*NDH + d4*4);
            const float* qp = qs + h*NDH + d4*4;
            a0 += qp[0]*w4.x; a1 += qp[1]*w4.y; a2 += qp[2]*w4.z; a3 += qp[3]*w4.w;
        }
        qacc[h] = (a0+a1)+(a2+a3);
    }
    #pragma unroll
    for (int h = 0; h < NH; ++h) qe[((size_t)row*NH + h)*NDIM + t] = qacc[h];
    if (t < NH) {
        float a = 0.f;
        #pragma unroll 4
        for (int d = 0; d < NDH; ++d) a += qs[t*NDH + d]*be[t*NDH + d];
        qbe[(size_t)row*NH + t] = a;
    }
}

// ---------------------------------------------------------------------------
// K3: fused edge-attention per (b,i) row. Online softmax over j in chunks of 32.
// v2 (occupancy restructure):
//  - redbuf (37.5KB LDS) -> in-register 31-shuffle butterfly reduce-scatter;
//    each lane of a half-wave ends with one (j,h) partial -> simbuf (1.1KB).
//  - qe fragment (64 VGPRs) -> qe_s in LDS (8KB); q row -> qrow_s (1KB,
//    broadcast reads in phase 2). LDS 49152 -> ~12.5KB => 4 blocks/CU.
//  - next e-chunk prefetched into regs right after barrier A (hidden under
//    phase2+3); 2 barriers/chunk (loop-end barrier proven redundant).
//  - epilogue wfull/ovfull/oibuf alias the (dead) qe_s/qrow_s region.
// ---------------------------------------------------------------------------
__global__ __launch_bounds__(256, 4) void k_attn(
    const float* __restrict__ edges,
    const float* __restrict__ We, const float* __restrict__ be,
    const float* __restrict__ Wo, const float* __restrict__ bo,
    const float* __restrict__ q, const float* __restrict__ k, const float* __restrict__ v,
    const float* __restrict__ qe, const float* __restrict__ qbe,
    float* __restrict__ out)
{
    const int row = blockIdx.x;        // b*N + i
    const int b = row >> 9;            // N = 512
    const int t = threadIdx.x;
    // phase-1 mapping: gA = c-block (8 floats), sA = j-stride
    const int gA = t & 31, sA = t >> 5;
    // phase-2 mapping: jlB = j within chunk, hB = head (half-wave uniform)
    const int jlB = t & 31, hB = t >> 5;
    // phase-3 mapping: hC = head, cbC = c-block
    const int hC = t & 7,  cbC = t >> 3;
    const bool isv = (hC == (cbC >> 2));   // this thread also owns ov for its c-slice

    // main loop: qe_s [8][256] + qrow_s [256]; epilogue aliases the same block
    __shared__ __align__(16) float uni[2560];
    __shared__ __align__(16) float simbuf[32*9];   // [jl][h] stride 9: conflict-free
    __shared__ __align__(16) float pbuf[256];      // [jl][h]
    __shared__ float mh[8], lh[8], al[8];

    float* qe_s   = uni;            // 2048 floats
    float* qrow_s = uni + 2048;     // 256 floats

    const float* Erow = edges + (size_t)row*NN*NDIM;
    const float* krow = k + (size_t)b*NN*NDIM + hB*NDH;

    // prologue: issue e-chunk 0 loads first (longest latency)
    float4 ea[4], eb4[4];
    {
        const float* ep0 = Erow + (size_t)sA*NDIM + gA*8;
        #pragma unroll
        for (int m = 0; m < 4; ++m) {
            ea[m]  = *(const float4*)(ep0 + (size_t)m*8*NDIM);
            eb4[m] = *(const float4*)(ep0 + (size_t)m*8*NDIM + 4);
        }
    }
    // stage qe row (8KB) and q row (1KB) into LDS
    {
        const float* qp = qe + (size_t)row*(NH*NDIM) + t*8;
        float4 a0 = *(const float4*)(qp);
        float4 a1 = *(const float4*)(qp + 4);
        *(float4*)(qe_s + t*8)     = a0;
        *(float4*)(qe_s + t*8 + 4) = a1;
        qrow_s[t] = q[(size_t)row*NDIM + t];
    }
    const float qbeV = qbe[(size_t)row*NH + hB];
    float w_r[8], ov_r[8];
    #pragma unroll
    for (int r = 0; r < 8; ++r) { w_r[r] = 0.f; ov_r[r] = 0.f; }
    if (t < 8) { mh[t] = -1e30f; lh[t] = 0.f; }
    __syncthreads();

    for (int jc = 0; jc < 16; ++jc) {
        const int j0 = jc*32;
        // ---- phase 1: per-thread partials of edges.qe (8 c's x 8 heads x 4 j) ----
        float v32_[32];                // q-index = m*8 + h
        #pragma unroll
        for (int h = 0; h < 8; ++h) {
            const float4 qa = *(const float4*)(qe_s + h*NDIM + gA*8);
            const float4 qb = *(const float4*)(qe_s + h*NDIM + gA*8 + 4);
            #pragma unroll
            for (int m = 0; m < 4; ++m) {
                v32_[m*8+h] =
                    ea[m].x*qa.x + ea[m].y*qa.y + ea[m].z*qa.z + ea[m].w*qa.w +
                    eb4[m].x*qb.x + eb4[m].y*qb.y + eb4[m].z*qb.z + eb4[m].w*qb.w;
            }
        }
        // butterfly reduce-scatter over 32 lanes of the half-wave:
        // after 5 halving steps lane gA holds sum over c of q-index gA.
        float v16_[16];
        {
            const bool bb = (gA & 16) != 0;
            #pragma unroll
            for (int i = 0; i < 16; ++i) {
                const float lo = v32_[i], hi = v32_[i+16];
                const float ot = __shfl_xor(bb ? lo : hi, 16, 64);
                v16_[i] = (bb ? hi : lo) + ot;
            }
        }
        float v8_[8];
        {
            const bool bb = (gA & 8) != 0;
            #pragma unroll
            for (int i = 0; i < 8; ++i) {
                const float lo = v16_[i], hi = v16_[i+8];
                const float ot = __shfl_xor(bb ? lo : hi, 8, 64);
                v8_[i] = (bb ? hi : lo) + ot;
            }
        }
        float v4_[4];
        {
            const bool bb = (gA & 4) != 0;
            #pragma unroll
            for (int i = 0; i < 4; ++i) {
                const float lo = v8_[i], hi = v8_[i+4];
                const float ot = __shfl_xor(bb ? lo : hi, 4, 64);
                v4_[i] = (bb ? hi : lo) + ot;
            }
        }
        float v2_[2];
        {
            const bool bb = (gA & 2) != 0;
            #pragma unroll
            for (int i = 0; i < 2; ++i) {
                const float lo = v4_[i], hi = v4_[i+2];
                const float ot = __shfl_xor(bb ? lo : hi, 2, 64);
                v2_[i] = (bb ? hi : lo) + ot;
            }
        }
        float sacc;
        {
            const bool bb = (gA & 1) != 0;
            const float lo = v2_[0], hi = v2_[1];
            const float ot = __shfl_xor(bb ? lo : hi, 1, 64);
            sacc = (bb ? hi : lo) + ot;
        }
        // lane gA: h = gA&7, m = gA>>3, jl = sA + m*8  (all 32 banks distinct)
        simbuf[(sA + (gA >> 3)*8)*9 + (gA & 7)] = sacc;
        __syncthreads();   // A

        // ---- prefetch next e-chunk (hidden under phase 2+3) ----
        if (jc < 15) {
            const float* epn = Erow + (size_t)(j0 + 32 + sA)*NDIM + gA*8;
            #pragma unroll
            for (int m = 0; m < 4; ++m) {
                ea[m]  = *(const float4*)(epn + (size_t)m*8*NDIM);
                eb4[m] = *(const float4*)(epn + (size_t)m*8*NDIM + 4);
            }
        }

        // ---- phase 2: add q.k, online-softmax update ----
        {
            const int j = j0 + jlB;
            const float* kp = krow + (size_t)j*NDIM;
            const float* qp = qrow_s + hB*NDH;      // LDS broadcast (uniform addr)
            float d0=0.f,d1=0.f,d2=0.f,d3=0.f;
            #pragma unroll
            for (int u = 0; u < 8; ++u) {
                float4 kv4 = *(const float4*)(kp + u*4);
                float4 qv4 = *(const float4*)(qp + u*4);
                d0 += qv4.x*kv4.x; d1 += qv4.y*kv4.y;
                d2 += qv4.z*kv4.z; d3 += qv4.w*kv4.w;
            }
            const float sim = SCALE*(((d0+d1)+(d2+d3)) + qbeV + simbuf[jlB*9 + hB]);
            // butterfly over the 32 lanes of this half-wave (same hB)
            float cm = sim;
            #pragma unroll
            for (int off = 16; off >= 1; off >>= 1)
                cm = fmaxf(cm, __shfl_xor(cm, off, 64));
            const float mold = mh[hB];
            const float mnew = fmaxf(mold, cm);
            const float a_ = __expf(mold - mnew);
            const float p = __expf(sim - mnew);
            float ps = p;
            #pragma unroll
            for (int off = 16; off >= 1; off >>= 1)
                ps += __shfl_xor(ps, off, 64);
            if (jlB == 0) {           // lane 0 of half-wave; lockstep => no race
                mh[hB] = mnew;
                lh[hB] = lh[hB]*a_ + ps;
                al[hB] = a_;
            }
            pbuf[jlB*8 + hB] = p;
        }
        __syncthreads();   // B
        // ---- phase 3: rescale + accumulate w (edges again; L2 hit) and ov ----
        {
            const float a_ = al[hC];
            #pragma unroll
            for (int r = 0; r < 8; ++r) w_r[r] *= a_;
            if (isv) {
                #pragma unroll
                for (int r = 0; r < 8; ++r) ov_r[r] *= a_;
            }
            const float* eb = Erow + (size_t)j0*NDIM + cbC*8;
            const float* vb = v + ((size_t)b*NN + j0)*NDIM + cbC*8;
            #pragma unroll 4
            for (int jl = 0; jl < 32; ++jl) {
                const float p = pbuf[jl*8 + hC];
                float4 e0 = *(const float4*)(eb + (size_t)jl*NDIM);
                float4 e1 = *(const float4*)(eb + (size_t)jl*NDIM + 4);
                w_r[0] += p*e0.x; w_r[1] += p*e0.y; w_r[2] += p*e0.z; w_r[3] += p*e0.w;
                w_r[4] += p*e1.x; w_r[5] += p*e1.y; w_r[6] += p*e1.z; w_r[7] += p*e1.w;
                if (isv) {
                    float4 v0 = *(const float4*)(vb + (size_t)jl*NDIM);
                    float4 v1 = *(const float4*)(vb + (size_t)jl*NDIM + 4);
                    ov_r[0] += p*v0.x; ov_r[1] += p*v0.y; ov_r[2] += p*v0.z; ov_r[3] += p*v0.w;
                    ov_r[4] += p*v1.x; ov_r[5] += p*v1.y; ov_r[6] += p*v1.z; ov_r[7] += p*v1.w;
                }
            }
        }
        // no loop-end barrier: next phase1 writes only simbuf (phase3 never reads
        // it); pbuf/al reuse is ordered by barrier A of the next iteration.
    }

    // ---- epilogue (aliases uni: qe_s/qrow_s are dead past barrier B(15)) ----
    float* wfull  = uni;            // [8][256]
    float* ovfull = uni + 2048;     // [256]
    float* oibuf  = uni + 2304;     // [256]
    #pragma unroll
    for (int r = 0; r < 8; ++r) wfull[hC*NDIM + cbC*8 + r] = w_r[r];
    if (isv) {
        #pragma unroll
        for (int r = 0; r < 8; ++r) ovfull[cbC*8 + r] = ov_r[r];
    }
    __syncthreads();
    {
        const int u = t, hu = u >> 5;
        const float linv = 1.f/lh[hu];
        const float* wrow = wfull + hu*NDIM;
        float a0=0.f,a1=0.f,a2=0.f,a3=0.f;
        #pragma unroll 2
        for (int c = 0; c < NDIM; c += 4) {
            a0 += wrow[c+0]*We[(size_t)(c+0)*NDIM + u];
            a1 += wrow[c+1]*We[(size_t)(c+1)*NDIM + u];
            a2 += wrow[c+2]*We[(size_t)(c+2)*NDIM + u];
            a3 += wrow[c+3]*We[(size_t)(c+3)*NDIM + u];
        }
        oibuf[u] = (ovfull[u] + ((a0+a1)+(a2+a3)))*linv + be[u];
    }
    __syncthreads();
    {
        const int u = t;
        float a0=bo[u],a1=0.f,a2=0.f,a3=0.f;
        #pragma unroll 2
        for (int x = 0; x < NDIM; x += 4) {
            a0 += oibuf[x+0]*Wo[(size_t)(x+0)*NDIM + u];
            a1 += oibuf[x+1]*Wo[(size_t)(x+1)*NDIM + u];
            a2 += oibuf[x+2]*Wo[(size_t)(x+2)*NDIM + u];
            a3 += oibuf[x+3]*Wo[(size_t)(x+3)*NDIM + u];
        }
        out[(size_t)row*NDIM + u] = (a0+a1)+(a2+a3);
    }
}

extern "C" void kernel_launch(void* const* d_in, const int* in_sizes, int n_in,
                              void* d_out, int out_size, void* d_ws, size_t ws_size,
                              hipStream_t stream) {
    const float* nodes = (const float*)d_in[0];
    const float* edges = (const float*)d_in[1];
    const float* Wq  = (const float*)d_in[2];
    const float* bq  = (const float*)d_in[3];
    const float* Wkv = (const float*)d_in[4];
    const float* bkv = (const float*)d_in[5];
    const float* We  = (const float*)d_in[6];
    const float* be  = (const float*)d_in[7];
    const float* Wo  = (const float*)d_in[8];
    const float* bo  = (const float*)d_in[9];
    (void)in_sizes; (void)n_in; (void)out_size; (void)ws_size;

    float* ws  = (float*)d_ws;
    float* q   = ws;                       // 2*512*256          = 262144 f32
    float* k   = q  + 262144;              // 262144
    float* v   = k  + 262144;              // 262144
    float* qe  = v  + 262144;              // 2*512*8*256        = 2097152
    float* qbe = qe + 2097152;             // 2*512*8            = 8192
    // total ~11.6 MB of d_ws

    k_proj<<<dim3(NB*NN), dim3(256), 0, stream>>>(nodes, Wq, bq, Wkv, bkv, We, be,
                                                  q, k, v, qe, qbe);
    k_attn<<<dim3(NB*NN), dim3(256), 0, stream>>>(edges, We, be, Wo, bo,
                                                  q, k, v, qe, qbe,
                                                  (float*)d_out);
}

// Round 2
// 927.629 us; speedup vs baseline: 1.2264x; 1.1018x over previous
//
#include <hip/hip_runtime.h>
#include <hip/hip_bf16.h>
#include <stdint.h>

// Problem constants (B=2, N=512, DIM=INNER=EDGE_DIM=256, H=8, DH=32)
#define NB 2
#define NN 512
#define NDIM 256
#define NH 8
#define NDH 32
#define SCALE 0.17677669529663687f  // 32^-0.5

// ---------------------------------------------------------------------------
// K1: per-row projections (all f32). v3: 2 rows per block — each weight load
// feeds 6 FMAs (was 3), halving L2 weight traffic and load-latency exposure.
// ---------------------------------------------------------------------------
__global__ __launch_bounds__(256) void k_proj(
    const float* __restrict__ nodes, const float* __restrict__ Wq, const float* __restrict__ bq,
    const float* __restrict__ Wkv, const float* __restrict__ bkv,
    const float* __restrict__ We, const float* __restrict__ be,
    float* __restrict__ q, float* __restrict__ k, float* __restrict__ v,
    float* __restrict__ qe, float* __restrict__ qbe)
{
    const int row0 = blockIdx.x * 2;   // two rows per block
    const int t = threadIdx.x;
    __shared__ float xs[2][NDIM];
    __shared__ float qs[2][NDIM];
    xs[0][t] = nodes[(size_t)row0*NDIM + t];
    xs[1][t] = nodes[(size_t)(row0+1)*NDIM + t];
    __syncthreads();

    float accq0 = bq[t],        accq1 = bq[t];
    float acck0 = bkv[t],       acck1 = bkv[t];
    float accv0 = bkv[t+NDIM],  accv1 = bkv[t+NDIM];
    #pragma unroll 8
    for (int d = 0; d < NDIM; ++d) {
        const float w0 = Wq [(size_t)d*NDIM + t];
        const float w1 = Wkv[(size_t)d*2*NDIM + t];
        const float w2 = Wkv[(size_t)d*2*NDIM + t + NDIM];
        const float x0 = xs[0][d], x1 = xs[1][d];
        accq0 += x0*w0; accq1 += x1*w0;
        acck0 += x0*w1; acck1 += x1*w1;
        accv0 += x0*w2; accv1 += x1*w2;
    }
    q[(size_t)row0*NDIM + t] = accq0;  q[(size_t)(row0+1)*NDIM + t] = accq1;
    k[(size_t)row0*NDIM + t] = acck0;  k[(size_t)(row0+1)*NDIM + t] = acck1;
    v[(size_t)row0*NDIM + t] = accv0;  v[(size_t)(row0+1)*NDIM + t] = accv1;
    qs[0][t] = accq0; qs[1][t] = accq1;
    __syncthreads();

    // qe: thread t owns We row c=t (contiguous 1KB -> float4 loads), both rows
    const float* wrow = We + (size_t)t*NDIM;
    #pragma unroll
    for (int h = 0; h < NH; ++h) {
        float a0 = 0.f, a1 = 0.f, b0 = 0.f, b1 = 0.f;
        #pragma unroll
        for (int d4 = 0; d4 < NDH/4; ++d4) {
            float4 w4 = *(const float4*)(wrow + h*NDH + d4*4);
            const float* qp0 = &qs[0][h*NDH + d4*4];
            const float* qp1 = &qs[1][h*NDH + d4*4];
            a0 += qp0[0]*w4.x + qp0[1]*w4.y;
            a1 += qp0[2]*w4.z + qp0[3]*w4.w;
            b0 += qp1[0]*w4.x + qp1[1]*w4.y;
            b1 += qp1[2]*w4.z + qp1[3]*w4.w;
        }
        qe[((size_t)row0*NH + h)*NDIM + t]     = a0 + a1;
        qe[((size_t)(row0+1)*NH + h)*NDIM + t] = b0 + b1;
    }
    if (t < 2*NH) {
        const int r = t >> 3, h = t & 7;
        float a = 0.f;
        #pragma unroll 4
        for (int d = 0; d < NDH; ++d) a += qs[r][h*NDH + d]*be[h*NDH + d];
        qbe[(size_t)(row0+r)*NH + h] = a;
    }
}

// ---------------------------------------------------------------------------
// K3: fused edge-attention per (b,i) row. Online softmax over j in chunks of 32.
// v3 (phase-3 de-duplication):
//  - phase 3 thread t owns COLUMN c=t: accumulates w[h][c] for all 8 h and
//    ov[c]. e[j][c]/v[j][c] read once per block (coalesced b32) instead of
//    8x-redundant b128 per (h,c-block): L2 traffic 288KB -> 64KB per chunk.
//  - pbuf row stride 8 -> 12 (16B-aligned): write conflict 16-way -> 4-way,
//    reads are aligned b128 broadcasts.
//  - epilogue w/ov mapping updated to column ownership.
// ---------------------------------------------------------------------------
__global__ __launch_bounds__(256, 4) void k_attn(
    const float* __restrict__ edges,
    const float* __restrict__ We, const float* __restrict__ be,
    const float* __restrict__ Wo, const float* __restrict__ bo,
    const float* __restrict__ q, const float* __restrict__ k, const float* __restrict__ v,
    const float* __restrict__ qe, const float* __restrict__ qbe,
    float* __restrict__ out)
{
    const int row = blockIdx.x;        // b*N + i
    const int b = row >> 9;            // N = 512
    const int t = threadIdx.x;
    // phase-1 mapping: gA = c-block (8 floats), sA = j-stride
    const int gA = t & 31, sA = t >> 5;
    // phase-2 mapping: jlB = j within chunk, hB = head (half-wave uniform)
    const int jlB = t & 31, hB = t >> 5;
    // phase-3 mapping: thread t owns column c = t; its ov head:
    const int hOwn = t >> 5;

    // main loop: qe_s [8][256] + qrow_s [256]; epilogue aliases the same block
    __shared__ __align__(16) float uni[2560];
    __shared__ __align__(16) float simbuf[32*9];   // [jl][h] stride 9: conflict-free
    __shared__ __align__(16) float pbuf[32*12];    // [jl][h] stride 12 (48B, 16B-aligned)
    __shared__ float mh[8], lh[8];
    __shared__ __align__(16) float al[8];

    float* qe_s   = uni;            // 2048 floats
    float* qrow_s = uni + 2048;     // 256 floats

    const float* Erow = edges + (size_t)row*NN*NDIM;
    const float* krow = k + (size_t)b*NN*NDIM + hB*NDH;

    // prologue: issue e-chunk 0 loads first (longest latency)
    float4 ea[4], eb4[4];
    {
        const float* ep0 = Erow + (size_t)sA*NDIM + gA*8;
        #pragma unroll
        for (int m = 0; m < 4; ++m) {
            ea[m]  = *(const float4*)(ep0 + (size_t)m*8*NDIM);
            eb4[m] = *(const float4*)(ep0 + (size_t)m*8*NDIM + 4);
        }
    }
    // stage qe row (8KB) and q row (1KB) into LDS
    {
        const float* qp = qe + (size_t)row*(NH*NDIM) + t*8;
        float4 a0 = *(const float4*)(qp);
        float4 a1 = *(const float4*)(qp + 4);
        *(float4*)(qe_s + t*8)     = a0;
        *(float4*)(qe_s + t*8 + 4) = a1;
        qrow_s[t] = q[(size_t)row*NDIM + t];
    }
    const float qbeV = qbe[(size_t)row*NH + hB];
    float w_r[8];
    float ov_r = 0.f;
    #pragma unroll
    for (int r = 0; r < 8; ++r) w_r[r] = 0.f;
    if (t < 8) { mh[t] = -1e30f; lh[t] = 0.f; }
    __syncthreads();

    for (int jc = 0; jc < 16; ++jc) {
        const int j0 = jc*32;
        // ---- phase 1: per-thread partials of edges.qe (8 c's x 8 heads x 4 j) ----
        float v32_[32];                // q-index = m*8 + h
        #pragma unroll
        for (int h = 0; h < 8; ++h) {
            const float4 qa = *(const float4*)(qe_s + h*NDIM + gA*8);
            const float4 qb = *(const float4*)(qe_s + h*NDIM + gA*8 + 4);
            #pragma unroll
            for (int m = 0; m < 4; ++m) {
                v32_[m*8+h] =
                    ea[m].x*qa.x + ea[m].y*qa.y + ea[m].z*qa.z + ea[m].w*qa.w +
                    eb4[m].x*qb.x + eb4[m].y*qb.y + eb4[m].z*qb.z + eb4[m].w*qb.w;
            }
        }
        // butterfly reduce-scatter over 32 lanes of the half-wave:
        // after 5 halving steps lane gA holds sum over c of q-index gA.
        float v16_[16];
        {
            const bool bb = (gA & 16) != 0;
            #pragma unroll
            for (int i = 0; i < 16; ++i) {
                const float lo = v32_[i], hi = v32_[i+16];
                const float ot = __shfl_xor(bb ? lo : hi, 16, 64);
                v16_[i] = (bb ? hi : lo) + ot;
            }
        }
        float v8_[8];
        {
            const bool bb = (gA & 8) != 0;
            #pragma unroll
            for (int i = 0; i < 8; ++i) {
                const float lo = v16_[i], hi = v16_[i+8];
                const float ot = __shfl_xor(bb ? lo : hi, 8, 64);
                v8_[i] = (bb ? hi : lo) + ot;
            }
        }
        float v4_[4];
        {
            const bool bb = (gA & 4) != 0;
            #pragma unroll
            for (int i = 0; i < 4; ++i) {
                const float lo = v8_[i], hi = v8_[i+4];
                const float ot = __shfl_xor(bb ? lo : hi, 4, 64);
                v4_[i] = (bb ? hi : lo) + ot;
            }
        }
        float v2_[2];
        {
            const bool bb = (gA & 2) != 0;
            #pragma unroll
            for (int i = 0; i < 2; ++i) {
                const float lo = v4_[i], hi = v4_[i+2];
                const float ot = __shfl_xor(bb ? lo : hi, 2, 64);
                v2_[i] = (bb ? hi : lo) + ot;
            }
        }
        float sacc;
        {
            const bool bb = (gA & 1) != 0;
            const float lo = v2_[0], hi = v2_[1];
            const float ot = __shfl_xor(bb ? lo : hi, 1, 64);
            sacc = (bb ? hi : lo) + ot;
        }
        // lane gA: h = gA&7, m = gA>>3, jl = sA + m*8  (all 32 banks distinct)
        simbuf[(sA + (gA >> 3)*8)*9 + (gA & 7)] = sacc;
        __syncthreads();   // A

        // ---- prefetch next e-chunk (hidden under phase 2+3) ----
        if (jc < 15) {
            const float* epn = Erow + (size_t)(j0 + 32 + sA)*NDIM + gA*8;
            #pragma unroll
            for (int m = 0; m < 4; ++m) {
                ea[m]  = *(const float4*)(epn + (size_t)m*8*NDIM);
                eb4[m] = *(const float4*)(epn + (size_t)m*8*NDIM + 4);
            }
        }

        // ---- phase 2: add q.k, online-softmax update ----
        {
            const int j = j0 + jlB;
            const float* kp = krow + (size_t)j*NDIM;
            const float* qp = qrow_s + hB*NDH;      // LDS broadcast (uniform addr)
            float d0=0.f,d1=0.f,d2=0.f,d3=0.f;
            #pragma unroll
            for (int u = 0; u < 8; ++u) {
                float4 kv4 = *(const float4*)(kp + u*4);
                float4 qv4 = *(const float4*)(qp + u*4);
                d0 += qv4.x*kv4.x; d1 += qv4.y*kv4.y;
                d2 += qv4.z*kv4.z; d3 += qv4.w*kv4.w;
            }
            const float sim = SCALE*(((d0+d1)+(d2+d3)) + qbeV + simbuf[jlB*9 + hB]);
            // butterfly over the 32 lanes of this half-wave (same hB)
            float cm = sim;
            #pragma unroll
            for (int off = 16; off >= 1; off >>= 1)
                cm = fmaxf(cm, __shfl_xor(cm, off, 64));
            const float mold = mh[hB];
            const float mnew = fmaxf(mold, cm);
            const float a_ = __expf(mold - mnew);
            const float p = __expf(sim - mnew);
            float ps = p;
            #pragma unroll
            for (int off = 16; off >= 1; off >>= 1)
                ps += __shfl_xor(ps, off, 64);
            if (jlB == 0) {           // lane 0 of half-wave; lockstep => no race
                mh[hB] = mnew;
                lh[hB] = lh[hB]*a_ + ps;
                al[hB] = a_;
            }
            pbuf[jlB*12 + hB] = p;
        }
        __syncthreads();   // B
        // ---- phase 3: column ownership — w[0..7][c=t] and ov[c=t] ----
        {
            const float4 al0 = *(const float4*)(al);
            const float4 al1 = *(const float4*)(al + 4);
            w_r[0]*=al0.x; w_r[1]*=al0.y; w_r[2]*=al0.z; w_r[3]*=al0.w;
            w_r[4]*=al1.x; w_r[5]*=al1.y; w_r[6]*=al1.z; w_r[7]*=al1.w;
            ov_r *= al[hOwn];
            const float* eb = Erow + (size_t)j0*NDIM + t;
            const float* vb = v + ((size_t)b*NN + j0)*NDIM + t;
            #pragma unroll 8
            for (int jl = 0; jl < 32; ++jl) {
                const float ee = eb[(size_t)jl*NDIM];       // coalesced b32, L2-hit
                const float vv = vb[(size_t)jl*NDIM];
                const float4 p0 = *(const float4*)(pbuf + jl*12);     // broadcast
                const float4 p1 = *(const float4*)(pbuf + jl*12 + 4); // broadcast
                const float pv = pbuf[jl*12 + hOwn];
                w_r[0] += p0.x*ee; w_r[1] += p0.y*ee; w_r[2] += p0.z*ee; w_r[3] += p0.w*ee;
                w_r[4] += p1.x*ee; w_r[5] += p1.y*ee; w_r[6] += p1.z*ee; w_r[7] += p1.w*ee;
                ov_r += pv*vv;
            }
        }
        // no loop-end barrier: next phase1 writes only simbuf (phase3 never reads
        // it); pbuf/al reuse is ordered by barrier A of the next iteration.
    }

    // ---- epilogue (aliases uni: qe_s/qrow_s are dead past barrier B(15)) ----
    float* wfull  = uni;            // [8][256]
    float* ovfull = uni + 2048;     // [256]
    float* oibuf  = uni + 2304;     // [256]
    #pragma unroll
    for (int h = 0; h < 8; ++h) wfull[h*NDIM + t] = w_r[h];   // lanes->cols: conflict-free
    ovfull[t] = ov_r;
    __syncthreads();
    {
        const int u = t, hu = u >> 5;
        const float linv = 1.f/lh[hu];
        const float* wrow = wfull + hu*NDIM;
        float a0=0.f,a1=0.f,a2=0.f,a3=0.f;
        #pragma unroll 2
        for (int c = 0; c < NDIM; c += 4) {
            a0 += wrow[c+0]*We[(size_t)(c+0)*NDIM + u];
            a1 += wrow[c+1]*We[(size_t)(c+1)*NDIM + u];
            a2 += wrow[c+2]*We[(size_t)(c+2)*NDIM + u];
            a3 += wrow[c+3]*We[(size_t)(c+3)*NDIM + u];
        }
        oibuf[u] = (ovfull[u] + ((a0+a1)+(a2+a3)))*linv + be[u];
    }
    __syncthreads();
    {
        const int u = t;
        float a0=bo[u],a1=0.f,a2=0.f,a3=0.f;
        #pragma unroll 2
        for (int x = 0; x < NDIM; x += 4) {
            a0 += oibuf[x+0]*Wo[(size_t)(x+0)*NDIM + u];
            a1 += oibuf[x+1]*Wo[(size_t)(x+1)*NDIM + u];
            a2 += oibuf[x+2]*Wo[(size_t)(x+2)*NDIM + u];
            a3 += oibuf[x+3]*Wo[(size_t)(x+3)*NDIM + u];
        }
        out[(size_t)row*NDIM + u] = (a0+a1)+(a2+a3);
    }
}

extern "C" void kernel_launch(void* const* d_in, const int* in_sizes, int n_in,
                              void* d_out, int out_size, void* d_ws, size_t ws_size,
                              hipStream_t stream) {
    const float* nodes = (const float*)d_in[0];
    const float* edges = (const float*)d_in[1];
    const float* Wq  = (const float*)d_in[2];
    const float* bq  = (const float*)d_in[3];
    const float* Wkv = (const float*)d_in[4];
    const float* bkv = (const float*)d_in[5];
    const float* We  = (const float*)d_in[6];
    const float* be  = (const float*)d_in[7];
    const float* Wo  = (const float*)d_in[8];
    const float* bo  = (const float*)d_in[9];
    (void)in_sizes; (void)n_in; (void)out_size; (void)ws_size;

    float* ws  = (float*)d_ws;
    float* q   = ws;                       // 2*512*256          = 262144 f32
    float* k   = q  + 262144;              // 262144
    float* v   = k  + 262144;              // 262144
    float* qe  = v  + 262144;              // 2*512*8*256        = 2097152
    float* qbe = qe + 2097152;             // 2*512*8            = 8192
    // total ~11.6 MB of d_ws

    k_proj<<<dim3(NB*NN/2), dim3(256), 0, stream>>>(nodes, Wq, bq, Wkv, bkv, We, be,
                                                    q, k, v, qe, qbe);
    k_attn<<<dim3(NB*NN), dim3(256), 0, stream>>>(edges, We, be, Wo, bo,
                                                  q, k, v, qe, qbe,
                                                  (float*)d_out);
}